// Round 4
// baseline (253.301 us; speedup 1.0000x reference)
//
#include <hip/hip_runtime.h>
#include <stdint.h>

// B=4, C=256, H=W=64, N=4096, CQK=16, Ktot=C*9=2304
// ws layout (11.82 MB):
//   qT  [4][4096][32] bf16   @ 0        (1 MiB)  slots0-15=hi(q), 16-31=lo residual
//   kT  [4][4096][32] bf16   @ 1 MiB    (1 MiB)  slots0-15=k,     16-31=k (dup)
//   Vb  [4][256][4096] bf16  @ 2 MiB    (8 MiB)
//   W2v [256][2304] bf16     @ 10 MiB   (1152 KiB)   k-order: (ci>>6)*576 + tap*64 + (ci&63)
//   W2q [16][2304]  bf16     @ +1179648 (72 KiB)
//   W2k [16][2304]  bf16     @ +73728   (72 KiB)

typedef __bf16 bf16;
typedef bf16 bf16x8 __attribute__((ext_vector_type(8)));
typedef float f32x4 __attribute__((ext_vector_type(4)));

#define DEV static __device__ __forceinline__

DEV f32x4 mfma16(bf16x8 a, bf16x8 b, f32x4 c) {
  return __builtin_amdgcn_mfma_f32_16x16x32_bf16(a, b, c, 0, 0, 0);
}

// ===================== weight pack =====================
__global__ void pack_w_kernel(const float* __restrict__ src, bf16* __restrict__ dst, int O) {
  int idx = blockIdx.x * 256 + threadIdx.x;
  if (idx >= O * 2304) return;
  int o = idx / 2304, r = idx - o * 2304;
  int ci = r / 9, tap = r - ci * 9;
  int kk = (ci >> 6) * 576 + tap * 64 + (ci & 63);
  dst[o * 2304 + kk] = (bf16)src[idx];
}

// ===================== conv staging (shared) =====================
// LDS tile: [dh 0..2][wHalo 0..65][cl 0..63] bf16, byte addr ^ ((wH&7)<<4) swizzle.
// Row = 64 cl * 2B = 128B -> XOR bits 4..6 stay in-row; b128 reads conflict-free.
DEV void stage_chunk(bf16* sm, const float* __restrict__ img, int b, int h, int ci0, int t) {
  // halo zeros (wH = 0 and 65)
  for (int idx = t; idx < 384; idx += 256) {
    int dh = idx >> 7, rr = idx & 127;
    int cl = rr & 63, wH = (rr >> 6) ? 65 : 0;
    uint32_t bo = ((((dh * 66 + wH) << 6) + cl) << 1) ^ ((wH & 7) << 4);
    *(bf16*)((char*)sm + bo) = (bf16)0.f;
  }
  const int wg = t & 15, clp = t >> 4;   // w-quad, cl-part
  for (int dh = 0; dh < 3; ++dh) {
    int hh = h + dh - 1;
    bool ok = (hh >= 0) && (hh < 64);
    for (int p = 0; p < 4; ++p) {
      int cl = (p << 4) + clp;
      int w0 = wg << 2;
      float4 xv = make_float4(0.f, 0.f, 0.f, 0.f);
      if (ok) xv = *(const float4*)&img[((((size_t)b << 8) + ci0 + cl) * 64 + hh) * 64 + w0];
      const float xs[4] = {xv.x, xv.y, xv.z, xv.w};
#pragma unroll
      for (int q4 = 0; q4 < 4; ++q4) {
        int wH = w0 + q4 + 1;
        uint32_t bo = ((((dh * 66 + wH) << 6) + cl) << 1) ^ ((wH & 7) << 4);
        *(bf16*)((char*)sm + bo) = (bf16)xs[q4];
      }
    }
  }
}

// ===================== conv q/k (O=16) =====================
// grid 256 = b(4)*h(64); block 256 (4 waves, wave w -> w-cols [16w,16w+16))
// split=1: write (hi, residual); split=0: write (k, k)
__global__ __launch_bounds__(256) void conv_qk_kernel(
    const float* __restrict__ img, const bf16* __restrict__ W2,
    const float* __restrict__ bias, bf16* __restrict__ dstT, int split) {
  __shared__ __align__(16) bf16 sm[3 * 66 * 64];
  const int t = threadIdx.x;
  const int lane = t & 63, wv = t >> 6;
  const int g = lane >> 4, ln = lane & 15;
  const int b = blockIdx.x >> 6;
  const int h = blockIdx.x & 63;
  f32x4 acc = {0.f, 0.f, 0.f, 0.f};
  for (int chunk = 0; chunk < 4; ++chunk) {
    __syncthreads();
    stage_chunk(sm, img, b, h, chunk << 6, t);
    __syncthreads();
#pragma unroll
    for (int ks = 0; ks < 18; ++ks) {
      const int tap = ks >> 1, clb = (ks & 1) << 5;
      const int kh = tap / 3, kw = tap - kh * 3;
      const int wH = (wv << 4) + ln + kw;
      uint32_t bo = ((((kh * 66 + wH) << 6) + clb + (g << 3)) << 1) ^ ((wH & 7) << 4);
      bf16x8 bfr = *(const bf16x8*)((char*)sm + bo);
      bf16x8 afr = *(const bf16x8*)&W2[(size_t)ln * 2304 + chunk * 576 + (ks << 5) + (g << 3)];
      acc = mfma16(afr, bfr, acc);
    }
  }
  const int p = (h << 6) + (wv << 4) + ln;
  bf16* drow = dstT + (((size_t)b << 12) + p) * 32;
#pragma unroll
  for (int r = 0; r < 4; ++r) {
    int o = (g << 2) + r;
    float val = acc[r] + bias[o];
    bf16 hi = (bf16)val;
    drow[o] = hi;
    drow[16 + o] = split ? (bf16)(val - (float)hi) : hi;
  }
}

// ===================== conv v (O=256) =====================
// grid 512 = b(4)*h(64)*ohalf(2); block 256; wave -> o-range obase..obase+32
__global__ __launch_bounds__(256) void conv_v_kernel(
    const float* __restrict__ img, const bf16* __restrict__ W2,
    const float* __restrict__ bias, bf16* __restrict__ dst) {
  __shared__ __align__(16) bf16 sm[3 * 66 * 64];
  const int t = threadIdx.x;
  const int lane = t & 63, wv = t >> 6;
  const int g = lane >> 4, ln = lane & 15;
  const int raw = blockIdx.x;
  const int b = raw >> 7;
  const int h = (raw >> 1) & 63;
  const int oh = raw & 1;
  const int obase = (oh << 7) + (wv << 5);
  f32x4 acc[2][4];
#pragma unroll
  for (int of = 0; of < 2; ++of)
#pragma unroll
    for (int wf = 0; wf < 4; ++wf) acc[of][wf] = (f32x4){0.f, 0.f, 0.f, 0.f};
  for (int chunk = 0; chunk < 4; ++chunk) {
    __syncthreads();
    stage_chunk(sm, img, b, h, chunk << 6, t);
    __syncthreads();
#pragma unroll
    for (int ks = 0; ks < 18; ++ks) {
      const int tap = ks >> 1, clb = (ks & 1) << 5;
      const int kh = tap / 3, kw = tap - kh * 3;
      bf16x8 bfr[4];
#pragma unroll
      for (int wf = 0; wf < 4; ++wf) {
        int wH = (wf << 4) + ln + kw;
        uint32_t bo = ((((kh * 66 + wH) << 6) + clb + (g << 3)) << 1) ^ ((wH & 7) << 4);
        bfr[wf] = *(const bf16x8*)((char*)sm + bo);
      }
#pragma unroll
      for (int of = 0; of < 2; ++of) {
        bf16x8 afr = *(const bf16x8*)&W2[(size_t)(obase + (of << 4) + ln) * 2304 +
                                         chunk * 576 + (ks << 5) + (g << 3)];
#pragma unroll
        for (int wf = 0; wf < 4; ++wf) acc[of][wf] = mfma16(afr, bfr[wf], acc[of][wf]);
      }
    }
  }
#pragma unroll
  for (int of = 0; of < 2; ++of)
#pragma unroll
    for (int r = 0; r < 4; ++r) {
      int o = obase + (of << 4) + (g << 2) + r;
      float bvv = bias[o];
#pragma unroll
      for (int wf = 0; wf < 4; ++wf) {
        int p = (h << 6) + (wf << 4) + ln;
        dst[(((size_t)b << 8) + o) * 4096 + p] = (bf16)(acc[of][wf][r] + bvv);
      }
    }
}

// ===================== attention =====================
// grid 512 (XCD-swizzled: batch b -> XCD pair, so Vb[b] (2MB) is L2-resident).
// block 256 = 4 independent waves (no barriers). Wave owns c-range [64w,64w+64),
// i-tile = 32 rows. S^T = mfma(K,Q): D[j][i], col i = lane&15 -> softmax state per-lane.
// P (bf16) -> wave-private swizzled LDS; PV: D[c][i] = V x P^T, V frags straight from L2.
__global__ __launch_bounds__(256) void attn_kernel(
    const bf16* __restrict__ qT, const bf16* __restrict__ kT,
    const bf16* __restrict__ Vb, float* __restrict__ outp) {
  __shared__ __align__(16) char Plds[4 * 4096];
  const int raw = blockIdx.x;                 // 512
  const int b = (raw & 7) >> 1;               // batch -> XCD pair
  const int it = ((raw & 1) << 6) + (raw >> 3);
  const int i0 = it << 5;
  const int lane = threadIdx.x & 63, wv = threadIdx.x >> 6;
  const int g = lane >> 4, ln = lane & 15;
  const int cb = wv << 6;
  char* pbase = Plds + (wv << 12);
  const float NEG = -3.0e38f;

  bf16x8 bq[2];
#pragma unroll
  for (int f = 0; f < 2; ++f)
    bq[f] = *(const bf16x8*)&qT[(((size_t)b << 12) + i0 + (f << 4) + ln) * 32 + (g << 3)];

  f32x4 acc[4][2];
#pragma unroll
  for (int cf = 0; cf < 4; ++cf)
#pragma unroll
    for (int f = 0; f < 2; ++f) acc[cf][f] = (f32x4){0.f, 0.f, 0.f, 0.f};
  float mrun[2] = {NEG, NEG};
  float lsum[2] = {0.f, 0.f};

  for (int jt = 0; jt < 64; ++jt) {
    const int j0 = jt << 6;
    bf16x8 ak[4];
#pragma unroll
    for (int jf = 0; jf < 4; ++jf)
      ak[jf] = *(const bf16x8*)&kT[(((size_t)b << 12) + j0 + (jf << 4) + ln) * 32 + (g << 3)];
    f32x4 s[4][2];
#pragma unroll
    for (int jf = 0; jf < 4; ++jf)
#pragma unroll
      for (int f = 0; f < 2; ++f) {
        f32x4 z = {0.f, 0.f, 0.f, 0.f};
        s[jf][f] = mfma16(ak[jf], bq[f], z);   // S^T[j][i], j=jf*16+g*4+r, i=f*16+ln
      }
#pragma unroll
    for (int f = 0; f < 2; ++f) {
      float mt = NEG;
#pragma unroll
      for (int jf = 0; jf < 4; ++jf)
#pragma unroll
        for (int r = 0; r < 4; ++r) mt = fmaxf(mt, s[jf][f][r]);
      mt = fmaxf(mt, __shfl_xor(mt, 16, 64));
      mt = fmaxf(mt, __shfl_xor(mt, 32, 64));
      float mnew = fmaxf(mrun[f], mt);
      float sc = __expf(mrun[f] - mnew);
      mrun[f] = mnew;
      float ts = 0.f;
      const int iloc = (f << 4) + ln;
#pragma unroll
      for (int jf = 0; jf < 4; ++jf) {
        union { bf16 h[4]; unsigned long long v; } pk;
#pragma unroll
        for (int r = 0; r < 4; ++r) {
          float pv = __expf(s[jf][f][r] - mnew);
          ts += pv;
          pk.h[r] = (bf16)pv;
        }
        uint32_t bo = ((uint32_t)(iloc << 7) + (jf << 5) + (g << 3)) ^ ((iloc & 7) << 4);
        *(unsigned long long*)(pbase + bo) = pk.v;
      }
      ts += __shfl_xor(ts, 16, 64);
      ts += __shfl_xor(ts, 32, 64);
      lsum[f] = lsum[f] * sc + ts;
#pragma unroll
      for (int cf = 0; cf < 4; ++cf) acc[cf][f] = acc[cf][f] * sc;
    }
    // PV: acc[c][i] += V[c, j0+ks*32+...] * P^T
#pragma unroll
    for (int ks = 0; ks < 2; ++ks) {
      bf16x8 bp[2];
#pragma unroll
      for (int f = 0; f < 2; ++f) {
        const int iloc = (f << 4) + ln;
        uint32_t bo = ((uint32_t)(iloc << 7) + (ks << 6) + (g << 4)) ^ ((iloc & 7) << 4);
        bp[f] = *(const bf16x8*)(pbase + bo);
      }
#pragma unroll
      for (int cf = 0; cf < 4; ++cf) {
        bf16x8 av = *(const bf16x8*)&Vb[(((size_t)b << 8) + cb + (cf << 4) + ln) * 4096 +
                                        j0 + (ks << 5) + (g << 3)];
#pragma unroll
        for (int f = 0; f < 2; ++f) acc[cf][f] = mfma16(av, bp[f], acc[cf][f]);
      }
    }
  }
  // epilogue: divide by lsum[i], store out[b][c][i] (16 lanes -> 64B contiguous)
#pragma unroll
  for (int f = 0; f < 2; ++f) {
    float rdiv = 1.f / lsum[f];
    int i = i0 + (f << 4) + ln;
#pragma unroll
    for (int cf = 0; cf < 4; ++cf)
#pragma unroll
      for (int r = 0; r < 4; ++r) {
        int c = cb + (cf << 4) + (g << 2) + r;
        outp[(((size_t)b << 8) + c) * 4096 + i] = acc[cf][f][r] * rdiv;
      }
  }
}

// ===================== launch =====================
extern "C" void kernel_launch(void* const* d_in, const int* in_sizes, int n_in,
                              void* d_out, int out_size, void* d_ws, size_t ws_size,
                              hipStream_t stream) {
  const float* x  = (const float*)d_in[0];
  const float* y  = (const float*)d_in[1];
  const float* wq = (const float*)d_in[2];
  const float* bq = (const float*)d_in[3];
  const float* wk = (const float*)d_in[4];
  const float* bk = (const float*)d_in[5];
  const float* wv = (const float*)d_in[6];
  const float* bv = (const float*)d_in[7];
  float* out = (float*)d_out;

  char* ws = (char*)d_ws;
  bf16* qT  = (bf16*)(ws);
  bf16* kT  = (bf16*)(ws + (1u << 20));
  bf16* Vb  = (bf16*)(ws + (2u << 20));
  bf16* W2v = (bf16*)(ws + (10u << 20));
  bf16* W2q = (bf16*)(ws + (10u << 20) + 1179648u);
  bf16* W2k = (bf16*)(ws + (10u << 20) + 1179648u + 73728u);

  pack_w_kernel<<<2304, 256, 0, stream>>>(wv, W2v, 256);
  pack_w_kernel<<<144, 256, 0, stream>>>(wq, W2q, 16);
  pack_w_kernel<<<144, 256, 0, stream>>>(wk, W2k, 16);

  conv_qk_kernel<<<256, 256, 0, stream>>>(x, W2q, bq, qT, 1);
  conv_qk_kernel<<<256, 256, 0, stream>>>(y, W2k, bk, kT, 0);
  conv_v_kernel<<<512, 256, 0, stream>>>(y, W2v, bv, Vb);

  attn_kernel<<<512, 256, 0, stream>>>(qT, kT, Vb, out);
}

// Round 5
// 244.130 us; speedup vs baseline: 1.0376x; 1.0376x over previous
//
#include <hip/hip_runtime.h>
#include <stdint.h>

// B=4, C=256, H=W=64, N=4096, CQK=16, Ktot=C*9=2304
// ws layout:
//   qT  [4][4096][64] bf16   @ 0        (2 MiB)  slots0-31=[qh|qh], 32-63=[ql|0], q pre-scaled by log2(e)
//   kT  [4][4096][32] bf16   @ 2 MiB    (1 MiB)  slots0-15=kh, 16-31=kl (residual)
//   Vb  [4][256][4096] bf16  @ 3 MiB    (8 MiB)
//   W2v [256][2304] bf16     @ 11 MiB   (1152 KiB)   k-order: (ci>>6)*576 + tap*64 + (ci&63)
//   W2q [16][2304]  bf16     @ +1179648 (72 KiB)
//   W2k [16][2304]  bf16     @ +73728   (72 KiB)

typedef __bf16 bf16;
typedef bf16 bf16x8 __attribute__((ext_vector_type(8)));
typedef float f32x4 __attribute__((ext_vector_type(4)));

#define DEV static __device__ __forceinline__

DEV f32x4 mfma16(bf16x8 a, bf16x8 b, f32x4 c) {
  return __builtin_amdgcn_mfma_f32_16x16x32_bf16(a, b, c, 0, 0, 0);
}

// ===================== weight pack (all 3 tensors, one launch) =====================
__global__ void pack_all_kernel(const float* __restrict__ wv, const float* __restrict__ wq,
                                const float* __restrict__ wk, bf16* __restrict__ W2v,
                                bf16* __restrict__ W2q, bf16* __restrict__ W2k) {
  int idx = blockIdx.x * 256 + threadIdx.x;
  if (idx >= 663552) return;
  const float* src;
  bf16* dst;
  int rel;
  if (idx < 589824)      { src = wv; dst = W2v; rel = idx; }
  else if (idx < 626688) { src = wq; dst = W2q; rel = idx - 589824; }
  else                   { src = wk; dst = W2k; rel = idx - 626688; }
  int o = rel / 2304, r = rel - o * 2304;
  int ci = r / 9, tap = r - ci * 9;
  int kk = (ci >> 6) * 576 + tap * 64 + (ci & 63);
  dst[o * 2304 + kk] = (bf16)src[rel];
}

// ===================== conv staging (shared) =====================
// LDS tile: [dh 0..2][wHalo 0..65][cl 0..63] bf16, byte addr ^ ((wH&7)<<4) swizzle.
DEV void stage_chunk(bf16* sm, const float* __restrict__ img, int b, int h, int ci0, int t) {
  for (int idx = t; idx < 384; idx += 256) {
    int dh = idx >> 7, rr = idx & 127;
    int cl = rr & 63, wH = (rr >> 6) ? 65 : 0;
    uint32_t bo = ((((dh * 66 + wH) << 6) + cl) << 1) ^ ((wH & 7) << 4);
    *(bf16*)((char*)sm + bo) = (bf16)0.f;
  }
  const int wg = t & 15, clp = t >> 4;
  for (int dh = 0; dh < 3; ++dh) {
    int hh = h + dh - 1;
    bool ok = (hh >= 0) && (hh < 64);
    for (int p = 0; p < 4; ++p) {
      int cl = (p << 4) + clp;
      int w0 = wg << 2;
      float4 xv = make_float4(0.f, 0.f, 0.f, 0.f);
      if (ok) xv = *(const float4*)&img[((((size_t)b << 8) + ci0 + cl) * 64 + hh) * 64 + w0];
      const float xs[4] = {xv.x, xv.y, xv.z, xv.w};
#pragma unroll
      for (int q4 = 0; q4 < 4; ++q4) {
        int wH = w0 + q4 + 1;
        uint32_t bo = ((((dh * 66 + wH) << 6) + cl) << 1) ^ ((wH & 7) << 4);
        *(bf16*)((char*)sm + bo) = (bf16)xs[q4];
      }
    }
  }
}

// ===================== conv q + k fused (O=16) =====================
// grid 512: blocks 0-255 q-mode (img=x, scale log2e, qT 64-wide), 256-511 k-mode (img=y, kT 32-wide)
__global__ __launch_bounds__(256) void conv_qk_kernel(
    const float* __restrict__ x, const float* __restrict__ y,
    const bf16* __restrict__ W2q, const bf16* __restrict__ W2k,
    const float* __restrict__ bq, const float* __restrict__ bk,
    bf16* __restrict__ qT, bf16* __restrict__ kT) {
  __shared__ __align__(16) bf16 sm[3 * 66 * 64];
  const int mode = blockIdx.x >> 8;       // 0=q, 1=k
  const float* img = mode ? y : x;
  const bf16* W2 = mode ? W2k : W2q;
  const float* bias = mode ? bk : bq;
  const int bi = blockIdx.x & 255;
  const int t = threadIdx.x;
  const int lane = t & 63, wv = t >> 6;
  const int g = lane >> 4, ln = lane & 15;
  const int b = bi >> 6;
  const int h = bi & 63;
  f32x4 acc = {0.f, 0.f, 0.f, 0.f};
  for (int chunk = 0; chunk < 4; ++chunk) {
    __syncthreads();
    stage_chunk(sm, img, b, h, chunk << 6, t);
    __syncthreads();
#pragma unroll
    for (int ks = 0; ks < 18; ++ks) {
      const int tap = ks >> 1, clb = (ks & 1) << 5;
      const int kh = tap / 3, kw = tap - kh * 3;
      const int wH = (wv << 4) + ln + kw;
      uint32_t bo = ((((kh * 66 + wH) << 6) + clb + (g << 3)) << 1) ^ ((wH & 7) << 4);
      bf16x8 bfr = *(const bf16x8*)((char*)sm + bo);
      bf16x8 afr = *(const bf16x8*)&W2[(size_t)ln * 2304 + chunk * 576 + (ks << 5) + (g << 3)];
      acc = mfma16(afr, bfr, acc);
    }
  }
  const int p = (h << 6) + (wv << 4) + ln;
#pragma unroll
  for (int r = 0; r < 4; ++r) {
    int o = (g << 2) + r;
    float val = acc[r] + bias[o];
    if (mode == 0) {
      val *= 1.4426950408889634f;              // log2(e): softmax via exp2
      bf16* drow = qT + (((size_t)b << 12) + p) * 64;
      bf16 hi = (bf16)val;
      drow[o] = hi;
      drow[16 + o] = hi;                       // B1 = [qh|qh]
      drow[32 + o] = (bf16)(val - (float)hi);  // B2 = [ql|0]
      drow[48 + o] = (bf16)0.f;
    } else {
      bf16* drow = kT + (((size_t)b << 12) + p) * 32;
      bf16 hi = (bf16)val;
      drow[o] = hi;                            // A = [kh|kl]
      drow[16 + o] = (bf16)(val - (float)hi);
    }
  }
}

// ===================== conv v (O=256) =====================
__global__ __launch_bounds__(256) void conv_v_kernel(
    const float* __restrict__ img, const bf16* __restrict__ W2,
    const float* __restrict__ bias, bf16* __restrict__ dst) {
  __shared__ __align__(16) bf16 sm[3 * 66 * 64];
  const int t = threadIdx.x;
  const int lane = t & 63, wv = t >> 6;
  const int g = lane >> 4, ln = lane & 15;
  const int raw = blockIdx.x;
  const int b = raw >> 7;
  const int h = (raw >> 1) & 63;
  const int oh = raw & 1;
  const int obase = (oh << 7) + (wv << 5);
  f32x4 acc[2][4];
#pragma unroll
  for (int of = 0; of < 2; ++of)
#pragma unroll
    for (int wf = 0; wf < 4; ++wf) acc[of][wf] = (f32x4){0.f, 0.f, 0.f, 0.f};
  for (int chunk = 0; chunk < 4; ++chunk) {
    __syncthreads();
    stage_chunk(sm, img, b, h, chunk << 6, t);
    __syncthreads();
#pragma unroll
    for (int ks = 0; ks < 18; ++ks) {
      const int tap = ks >> 1, clb = (ks & 1) << 5;
      const int kh = tap / 3, kw = tap - kh * 3;
      bf16x8 bfr[4];
#pragma unroll
      for (int wf = 0; wf < 4; ++wf) {
        int wH = (wf << 4) + ln + kw;
        uint32_t bo = ((((kh * 66 + wH) << 6) + clb + (g << 3)) << 1) ^ ((wH & 7) << 4);
        bfr[wf] = *(const bf16x8*)((char*)sm + bo);
      }
#pragma unroll
      for (int of = 0; of < 2; ++of) {
        bf16x8 afr = *(const bf16x8*)&W2[(size_t)(obase + (of << 4) + ln) * 2304 +
                                         chunk * 576 + (ks << 5) + (g << 3)];
#pragma unroll
        for (int wf = 0; wf < 4; ++wf) acc[of][wf] = mfma16(afr, bfr[wf], acc[of][wf]);
      }
    }
  }
#pragma unroll
  for (int of = 0; of < 2; ++of)
#pragma unroll
    for (int r = 0; r < 4; ++r) {
      int o = obase + (of << 4) + (g << 2) + r;
      float bvv = bias[o];
#pragma unroll
      for (int wf = 0; wf < 4; ++wf) {
        int p = (h << 6) + (wf << 4) + ln;
        dst[(((size_t)b << 8) + o) * 4096 + p] = (bf16)(acc[of][wf][r] + bvv);
      }
    }
}

// ===================== attention =====================
// grid 512 (batch -> XCD pair so Vb[b] L2-resident); 4 barrier-free waves, c-split.
// S^T = mfma(K,[qh|qh]) + mfma(K,[ql|0]) (fp32-grade energy, exp2 units).
// Defer-max (THR=8): per-lane pmax, __all ballot; rescale only on trigger.
// lsum per-lane, reduced once at end (2 shuffles total, not 2/tile).
__global__ __launch_bounds__(256) void attn_kernel(
    const bf16* __restrict__ qT, const bf16* __restrict__ kT,
    const bf16* __restrict__ Vb, float* __restrict__ outp) {
  __shared__ __align__(16) char Plds[4 * 4096];
  const int raw = blockIdx.x;                 // 512
  const int b = (raw & 7) >> 1;               // batch -> XCD pair
  const int it = ((raw & 1) << 6) + (raw >> 3);
  const int i0 = it << 5;
  const int lane = threadIdx.x & 63, wv = threadIdx.x >> 6;
  const int g = lane >> 4, ln = lane & 15;
  const int cb = wv << 6;
  char* pbase = Plds + (wv << 12);
  const float NEG = -3.0e38f;

  bf16x8 bq1[2], bq2[2];
#pragma unroll
  for (int f = 0; f < 2; ++f) {
    const bf16* qrow = &qT[(((size_t)b << 12) + i0 + (f << 4) + ln) * 64];
    bq1[f] = *(const bf16x8*)&qrow[g << 3];
    bq2[f] = *(const bf16x8*)&qrow[32 + (g << 3)];
  }

  f32x4 acc[4][2];
#pragma unroll
  for (int cf = 0; cf < 4; ++cf)
#pragma unroll
    for (int f = 0; f < 2; ++f) acc[cf][f] = (f32x4){0.f, 0.f, 0.f, 0.f};
  float mrun[2] = {NEG, NEG};
  float lsum[2] = {0.f, 0.f};    // per-lane partial (own 16 j per tile)

  for (int jt = 0; jt < 64; ++jt) {
    const int j0 = jt << 6;
    bf16x8 ak[4];
#pragma unroll
    for (int jf = 0; jf < 4; ++jf)
      ak[jf] = *(const bf16x8*)&kT[(((size_t)b << 12) + j0 + (jf << 4) + ln) * 32 + (g << 3)];
    f32x4 s[4][2];
#pragma unroll
    for (int jf = 0; jf < 4; ++jf)
#pragma unroll
      for (int f = 0; f < 2; ++f) {
        f32x4 z = {0.f, 0.f, 0.f, 0.f};
        s[jf][f] = mfma16(ak[jf], bq2[f], mfma16(ak[jf], bq1[f], z));
      }
#pragma unroll
    for (int f = 0; f < 2; ++f) {
      float pmax = NEG;
#pragma unroll
      for (int jf = 0; jf < 4; ++jf)
#pragma unroll
        for (int r = 0; r < 4; ++r) pmax = fmaxf(pmax, s[jf][f][r]);
      if (!__all(pmax - mrun[f] <= 8.f)) {   // rare: full rescale
        float mt = pmax;
        mt = fmaxf(mt, __shfl_xor(mt, 16, 64));
        mt = fmaxf(mt, __shfl_xor(mt, 32, 64));
        float mnew = fmaxf(mrun[f], mt);
        float sc = __builtin_amdgcn_exp2f(mrun[f] - mnew);
        mrun[f] = mnew;
        lsum[f] *= sc;
#pragma unroll
        for (int cf = 0; cf < 4; ++cf) acc[cf][f] = acc[cf][f] * sc;
      }
      const int iloc = (f << 4) + ln;
#pragma unroll
      for (int jf = 0; jf < 4; ++jf) {
        union { bf16 h[4]; unsigned long long v; } pk;
#pragma unroll
        for (int r = 0; r < 4; ++r) {
          float pv = __builtin_amdgcn_exp2f(s[jf][f][r] - mrun[f]);
          lsum[f] += pv;
          pk.h[r] = (bf16)pv;
        }
        uint32_t bo = ((uint32_t)(iloc << 7) + (jf << 5) + (g << 3)) ^ ((iloc & 7) << 4);
        *(unsigned long long*)(pbase + bo) = pk.v;
      }
    }
    // PV: acc[c][i] += V[c, j0+ks*32+...] * P^T
#pragma unroll
    for (int ks = 0; ks < 2; ++ks) {
      bf16x8 bp[2];
#pragma unroll
      for (int f = 0; f < 2; ++f) {
        const int iloc = (f << 4) + ln;
        uint32_t bo = ((uint32_t)(iloc << 7) + (ks << 6) + (g << 4)) ^ ((iloc & 7) << 4);
        bp[f] = *(const bf16x8*)(pbase + bo);
      }
#pragma unroll
      for (int cf = 0; cf < 4; ++cf) {
        bf16x8 av = *(const bf16x8*)&Vb[(((size_t)b << 8) + cb + (cf << 4) + ln) * 4096 +
                                        j0 + (ks << 5) + (g << 3)];
#pragma unroll
        for (int f = 0; f < 2; ++f) acc[cf][f] = mfma16(av, bp[f], acc[cf][f]);
      }
    }
  }
  // epilogue: reduce lsum over g (once), divide, store
#pragma unroll
  for (int f = 0; f < 2; ++f) {
    float l = lsum[f];
    l += __shfl_xor(l, 16, 64);
    l += __shfl_xor(l, 32, 64);
    float rdiv = 1.f / l;
    int i = i0 + (f << 4) + ln;
#pragma unroll
    for (int cf = 0; cf < 4; ++cf)
#pragma unroll
      for (int r = 0; r < 4; ++r) {
        int c = cb + (cf << 4) + (g << 2) + r;
        outp[(((size_t)b << 8) + c) * 4096 + i] = acc[cf][f][r] * rdiv;
      }
  }
}

// ===================== launch =====================
extern "C" void kernel_launch(void* const* d_in, const int* in_sizes, int n_in,
                              void* d_out, int out_size, void* d_ws, size_t ws_size,
                              hipStream_t stream) {
  const float* x  = (const float*)d_in[0];
  const float* y  = (const float*)d_in[1];
  const float* wq = (const float*)d_in[2];
  const float* bq = (const float*)d_in[3];
  const float* wk = (const float*)d_in[4];
  const float* bk = (const float*)d_in[5];
  const float* wv = (const float*)d_in[6];
  const float* bv = (const float*)d_in[7];
  float* out = (float*)d_out;

  char* ws = (char*)d_ws;
  bf16* qT  = (bf16*)(ws);
  bf16* kT  = (bf16*)(ws + (2u << 20));
  bf16* Vb  = (bf16*)(ws + (3u << 20));
  bf16* W2v = (bf16*)(ws + (11u << 20));
  bf16* W2q = (bf16*)(ws + (11u << 20) + 1179648u);
  bf16* W2k = (bf16*)(ws + (11u << 20) + 1179648u + 73728u);

  pack_all_kernel<<<2592, 256, 0, stream>>>(wv, wq, wk, W2v, W2q, W2k);
  conv_qk_kernel<<<512, 256, 0, stream>>>(x, y, W2q, W2k, bq, bk, qT, kT);
  conv_v_kernel<<<512, 256, 0, stream>>>(y, W2v, bv, Vb);
  attn_kernel<<<512, 256, 0, stream>>>(qT, kT, Vb, out);
}